// Round 5
// baseline (2512.768 us; speedup 1.0000x reference)
//
#include <hip/hip_runtime.h>
#include <hip/hip_bf16.h>
#include <math.h>

#define BB 8
#define TT 512
#define VV 50257
#define NN 768
#define HH 12
#define LL 12
#define MM (BB*TT)   // 4096 rows

typedef short bf16x8 __attribute__((ext_vector_type(8)));
typedef float f32x4 __attribute__((ext_vector_type(4)));
typedef unsigned short us8 __attribute__((ext_vector_type(8)));

__device__ __forceinline__ float bf2f(unsigned short u) {
    union { unsigned int i; float f; } x; x.i = ((unsigned int)u) << 16; return x.f;
}
__device__ __forceinline__ unsigned short f2bf(float f) {
    union { __hip_bfloat16 h; unsigned short u; } c; c.h = __float2bfloat16(f); return c.u;
}

// ---------------- embedding: x0 = wte[idx] + wpe ; h = x0 ----------------
__global__ void embed_kernel(const int* __restrict__ idx, const float* __restrict__ wte,
                             const float* __restrict__ wpe, float* __restrict__ x0,
                             float* __restrict__ h)
{
    int row = blockIdx.x;
    int t = row % TT;
    int tok = idx[row];
    const float* wt = wte + (size_t)tok * NN;
    const float* wp = wpe + (size_t)t * NN;
    float* px = x0 + (size_t)row * NN;
    float* ph = h  + (size_t)row * NN;
    for (int c = threadIdx.x; c < NN; c += blockDim.x) {
        float v = wt[c] + wp[c];
        px[c] = v; ph[c] = v;
    }
}

// ---------------- weight convert+transpose: W[K][Nc] fp32 -> Wt[Nc][K] bf16 ----------------
__global__ __launch_bounds__(256) void wconv_kernel(const float* __restrict__ W,
                                                    unsigned short* __restrict__ Wt,
                                                    int K, int Nc)
{
    __shared__ float tile[32][33];
    int n0 = blockIdx.x * 32, k0 = blockIdx.y * 32;
    int tid = threadIdx.x;
    int r = tid >> 3, c4 = (tid & 7) * 4;
    float4 v = *(const float4*)&W[(size_t)(k0 + r) * Nc + n0 + c4];
    tile[r][c4 + 0] = v.x; tile[r][c4 + 1] = v.y;
    tile[r][c4 + 2] = v.z; tile[r][c4 + 3] = v.w;
    __syncthreads();
    ushort4 o;
    o.x = f2bf(tile[c4 + 0][r]); o.y = f2bf(tile[c4 + 1][r]);
    o.z = f2bf(tile[c4 + 2][r]); o.w = f2bf(tile[c4 + 3][r]);
    *(ushort4*)&Wt[(size_t)(n0 + r) * K + k0 + c4] = o;
}

// ---------------- layernorm; ADD3 fuses hin = h + x0 + se ----------------
template<bool ADD3, typename OutT>
__global__ __launch_bounds__(256) void ln_kernel(
    const float* __restrict__ src, const float* __restrict__ x0,
    const float* __restrict__ se, const float* __restrict__ w,
    float* __restrict__ hin_out, OutT* __restrict__ out)
{
    int row = blockIdx.x;
    size_t base = (size_t)row * NN;
    int tid = threadIdx.x;
    float v[3];
    float s = 0.f, ss = 0.f;
#pragma unroll
    for (int i = 0; i < 3; ++i) {
        int c = tid + i * 256;
        float val = src[base + c];
        if (ADD3) { val += x0[base + c] + se[c]; hin_out[base + c] = val; }
        v[i] = val; s += val; ss += val * val;
    }
#pragma unroll
    for (int off = 32; off; off >>= 1) { s += __shfl_xor(s, off); ss += __shfl_xor(ss, off); }
    __shared__ float rs[4], rss[4], bc[2];
    int wid = tid >> 6, lane = tid & 63;
    if (lane == 0) { rs[wid] = s; rss[wid] = ss; }
    __syncthreads();
    if (tid == 0) {
        float S  = rs[0] + rs[1] + rs[2] + rs[3];
        float SS = rss[0] + rss[1] + rss[2] + rss[3];
        float mu = S / (float)NN;
        float var = SS / (float)NN - mu * mu;
        bc[0] = mu; bc[1] = rsqrtf(var + 1e-5f);
    }
    __syncthreads();
    float mu = bc[0], rsig = bc[1];
#pragma unroll
    for (int i = 0; i < 3; ++i) {
        int c = tid + i * 256;
        float o = (v[i] - mu) * rsig * w[c];
        if constexpr (sizeof(OutT) == 2) out[base + c] = (OutT)f2bf(o);
        else out[base + c] = o;
    }
}

// ---------------- bf16 MFMA GEMM, 2-phase double-buffered; BN in {64,128} ----------------
// C[M,N] = A[M,K] @ Bt[N,K]^T ; EPI: 0 none, 1 exact GELU, 2 residual add
template<int BN, int EPI, typename OutT>
__global__ __launch_bounds__(256) void mgemm(
    const unsigned short* __restrict__ A, const unsigned short* __restrict__ Bt,
    const float* __restrict__ res, OutT* __restrict__ C, int N, int K)
{
    constexpr int NF = BN / 32;              // col fragments per wave
    __shared__ unsigned short Asb[2][128 * 32];
    __shared__ unsigned short Bsb[2][BN * 32];
    int tid = threadIdx.x;
    int row0 = blockIdx.y * 128, col0 = blockIdx.x * BN;
    const unsigned short* Ap = A + (size_t)row0 * K;
    const unsigned short* Bp = Bt + (size_t)col0 * K;
    int lane = tid & 63, wid = tid >> 6;
    int wr = wid >> 1, wc = wid & 1;
    int fr = lane & 15, fq = lane >> 4;

    f32x4 acc[4][NF];
#pragma unroll
    for (int m = 0; m < 4; ++m)
#pragma unroll
        for (int n = 0; n < NF; ++n)
#pragma unroll
            for (int r = 0; r < 4; ++r) acc[m][n][r] = 0.f;

    int ldso = (tid & 192) * 8;   // wave-uniform LDS base (elems); HW adds lane*16B

    auto STAGE = [&](int buf, int k0) {
#pragma unroll
        for (int i = 0; i < 2; ++i) {
            int c = i * 256 + tid;              // row = c>>2, 16B piece = c&3
            __builtin_amdgcn_global_load_lds(
                (const __attribute__((address_space(1))) void*)(Ap + (size_t)(c >> 2) * K + k0 + (c & 3) * 8),
                (__attribute__((address_space(3))) void*)(Asb[buf] + i * 2048 + ldso), 16, 0, 0);
        }
        if constexpr (BN == 128) {
#pragma unroll
            for (int i = 0; i < 2; ++i) {
                int c = i * 256 + tid;
                __builtin_amdgcn_global_load_lds(
                    (const __attribute__((address_space(1))) void*)(Bp + (size_t)(c >> 2) * K + k0 + (c & 3) * 8),
                    (__attribute__((address_space(3))) void*)(Bsb[buf] + i * 2048 + ldso), 16, 0, 0);
            }
        } else {
            __builtin_amdgcn_global_load_lds(
                (const __attribute__((address_space(1))) void*)(Bp + (size_t)(tid >> 2) * K + k0 + (tid & 3) * 8),
                (__attribute__((address_space(3))) void*)(Bsb[buf] + ldso), 16, 0, 0);
        }
    };

    int NT = K / 32;
    STAGE(0, 0);
    asm volatile("s_waitcnt vmcnt(0)" ::: "memory");
    __syncthreads();

    int cur = 0;
    for (int t = 0; t < NT; ++t) {
        if (t + 1 < NT) STAGE(cur ^ 1, (t + 1) * 32);   // prefetch overlaps compute below
        const unsigned short* Ab = Asb[cur] + (wr * 64 + fr) * 32 + fq * 8;
        const unsigned short* Bb = Bsb[cur] + (wc * (BN / 2) + fr) * 32 + fq * 8;
        bf16x8 af[4], bfr[NF];
#pragma unroll
        for (int m = 0; m < 4; ++m) af[m] = *(const bf16x8*)(Ab + m * 512);
#pragma unroll
        for (int n = 0; n < NF; ++n) bfr[n] = *(const bf16x8*)(Bb + n * 512);
        __builtin_amdgcn_s_setprio(1);
#pragma unroll
        for (int m = 0; m < 4; ++m)
#pragma unroll
            for (int n = 0; n < NF; ++n)
                acc[m][n] = __builtin_amdgcn_mfma_f32_16x16x32_bf16(af[m], bfr[n], acc[m][n], 0, 0, 0);
        __builtin_amdgcn_s_setprio(0);
        asm volatile("s_waitcnt vmcnt(0)" ::: "memory");
        __syncthreads();
        cur ^= 1;
    }

#pragma unroll
    for (int m = 0; m < 4; ++m) {
#pragma unroll
        for (int n = 0; n < NF; ++n) {
            int col = col0 + wc * (BN / 2) + n * 16 + fr;
#pragma unroll
            for (int r = 0; r < 4; ++r) {
                int row = row0 + wr * 64 + m * 16 + fq * 4 + r;
                float v = acc[m][n][r];
                if (EPI == 1) v = 0.5f * v * (1.0f + erff(v * 0.70710678118654752f));
                if (EPI == 2) v += res[(size_t)row * N + col];
                if constexpr (sizeof(OutT) == 2) C[(size_t)row * N + col] = (OutT)f2bf(v);
                else C[(size_t)row * N + col] = v;
            }
        }
    }
}

// ---------------- V transpose: big V-section -> vT[(b*H+h)*64 + d][t] ----------------
__global__ __launch_bounds__(256) void vtrans_kernel(const unsigned short* __restrict__ qkv,
                                                     unsigned short* __restrict__ vT)
{
    int tt = blockIdx.x, h = blockIdx.y, b = blockIdx.z;
    int tid = threadIdx.x;
    __shared__ unsigned short T[64 * 72];
    {   // load 64 t-rows x 64 d (coalesced)
        int r = tid >> 2, c0 = (tid & 3) * 16;
        const us8* sp = (const us8*)&qkv[(size_t)(b * TT + tt * 64 + r) * 2304 + 1536 + h * 64 + c0];
        *(us8*)&T[r * 72 + c0] = sp[0];
        *(us8*)&T[r * 72 + c0 + 8] = sp[1];
    }
    __syncthreads();
    {   // write transposed: thread (d, tc) emits 16 consecutive t
        int d = tid & 63, tc = tid >> 6;
        unsigned short v[16];
#pragma unroll
        for (int i = 0; i < 16; ++i) v[i] = T[(tc * 16 + i) * 72 + d];
        unsigned short* dst = vT + ((size_t)(b * HH + h) * 64 + d) * TT + tt * 64 + tc * 16;
        *(us8*)dst = *(const us8*)&v[0];
        *(us8*)(dst + 8) = *(const us8*)&v[8];
    }
}

// ---------------- flash MFMA attention, no LDS staging (K/V are L2-resident) ----------------
// grid (T/64, H, B), 4 waves; wave w owns q-rows [qt*64+w*16, +16).
// K fragments read per-lane from qkv; V^T fragments from vT. Only Ps (wave-private) in LDS.
__global__ __launch_bounds__(256) void fattn_kernel(const unsigned short* __restrict__ qkv,
                                                    const unsigned short* __restrict__ vT,
                                                    unsigned short* __restrict__ y)
{
    int qt = blockIdx.x, h = blockIdx.y, b = blockIdx.z;
    int tid = threadIdx.x, lane = tid & 63, w = tid >> 6;
    int fr = lane & 15, fq = lane >> 4;

    __shared__ unsigned short Ps[64 * 72];

    int qrow = qt * 64 + w * 16 + fr;
    const unsigned short* qp = qkv + (size_t)(b * TT + qrow) * 2304 + h * 64 + fq * 8;
    bf16x8 qf0 = *(const bf16x8*)qp;
    bf16x8 qf1 = *(const bf16x8*)(qp + 32);

    // per-lane K row pointers (row j = n*16+fr), advance by 64 rows per tile
    const unsigned short* kp[4];
#pragma unroll
    for (int n = 0; n < 4; ++n)
        kp[n] = qkv + (size_t)(b * TT + n * 16 + fr) * 2304 + 768 + h * 64 + fq * 8;
    // per-lane V^T row pointers (row d = n*16+fr), advance by 64 cols per tile
    const unsigned short* vp[4];
#pragma unroll
    for (int n = 0; n < 4; ++n)
        vp[n] = vT + ((size_t)(b * HH + h) * 64 + n * 16 + fr) * TT + fq * 8;

    f32x4 acco[4];
#pragma unroll
    for (int n = 0; n < 4; ++n)
#pragma unroll
        for (int r = 0; r < 4; ++r) acco[n][r] = 0.f;
    float mrow[4] = {-1e30f, -1e30f, -1e30f, -1e30f};
    float lrow[4] = {0.f, 0.f, 0.f, 0.f};

    for (int kt = 0; kt <= qt; ++kt) {
        // K fragments direct from global (L2)
        bf16x8 kf0[4], kf1[4];
#pragma unroll
        for (int n = 0; n < 4; ++n) {
            const unsigned short* kr = kp[n] + (size_t)kt * 64 * 2304;
            kf0[n] = *(const bf16x8*)kr;
            kf1[n] = *(const bf16x8*)(kr + 32);
        }
        f32x4 accs[4];
#pragma unroll
        for (int n = 0; n < 4; ++n)
#pragma unroll
            for (int r = 0; r < 4; ++r) accs[n][r] = 0.f;
        __builtin_amdgcn_s_setprio(1);
#pragma unroll
        for (int n = 0; n < 4; ++n) {
            accs[n] = __builtin_amdgcn_mfma_f32_16x16x32_bf16(qf0, kf0[n], accs[n], 0, 0, 0);
            accs[n] = __builtin_amdgcn_mfma_f32_16x16x32_bf16(qf1, kf1[n], accs[n], 0, 0, 0);
        }
        __builtin_amdgcn_s_setprio(0);

        bool diag = (kt == qt);
#pragma unroll
        for (int n = 0; n < 4; ++n) {
            int j = kt * 64 + n * 16 + fr;
#pragma unroll
            for (int r = 0; r < 4; ++r) {
                float s = accs[n][r] * 0.125f;
                if (diag) { int q = qt * 64 + w * 16 + fq * 4 + r; if (j > q) s = -1e30f; }
                accs[n][r] = s;
            }
        }

        // online softmax (reduce across the 16 fr lanes per q-row)
        float rmax[4], psum[4];
#pragma unroll
        for (int r = 0; r < 4; ++r) {
            float m = fmaxf(fmaxf(accs[0][r], accs[1][r]), fmaxf(accs[2][r], accs[3][r]));
#pragma unroll
            for (int off = 8; off; off >>= 1) m = fmaxf(m, __shfl_xor(m, off));
            rmax[r] = m;
        }
        float fac[4];
#pragma unroll
        for (int r = 0; r < 4; ++r) {
            float mn = fmaxf(mrow[r], rmax[r]);
            fac[r] = __expf(mrow[r] - mn);
            mrow[r] = mn;
            psum[r] = 0.f;
        }
#pragma unroll
        for (int n = 0; n < 4; ++n)
#pragma unroll
            for (int r = 0; r < 4; ++r) {
                float p = __expf(accs[n][r] - mrow[r]);
                accs[n][r] = p;
                psum[r] += p;
            }
#pragma unroll
        for (int r = 0; r < 4; ++r) {
#pragma unroll
            for (int off = 8; off; off >>= 1) psum[r] += __shfl_xor(psum[r], off);
            lrow[r] = lrow[r] * fac[r] + psum[r];
        }

        // P -> LDS (wave-private rows), rescale O
#pragma unroll
        for (int n = 0; n < 4; ++n)
#pragma unroll
            for (int r = 0; r < 4; ++r)
                Ps[(w * 16 + fq * 4 + r) * 72 + n * 16 + fr] = f2bf(accs[n][r]);
#pragma unroll
        for (int n = 0; n < 4; ++n)
#pragma unroll
            for (int r = 0; r < 4; ++r) acco[n][r] *= fac[r];

        bf16x8 pf0 = *(const bf16x8*)&Ps[(w * 16 + fr) * 72 + fq * 8];
        bf16x8 pf1 = *(const bf16x8*)&Ps[(w * 16 + fr) * 72 + 32 + fq * 8];
        bf16x8 vf0[4], vf1[4];
#pragma unroll
        for (int n = 0; n < 4; ++n) {
            const unsigned short* vr = vp[n] + kt * 64;
            vf0[n] = *(const bf16x8*)vr;
            vf1[n] = *(const bf16x8*)(vr + 32);
        }
        __builtin_amdgcn_s_setprio(1);
#pragma unroll
        for (int n = 0; n < 4; ++n) {
            acco[n] = __builtin_amdgcn_mfma_f32_16x16x32_bf16(pf0, vf0[n], acco[n], 0, 0, 0);
            acco[n] = __builtin_amdgcn_mfma_f32_16x16x32_bf16(pf1, vf1[n], acco[n], 0, 0, 0);
        }
        __builtin_amdgcn_s_setprio(0);
    }

#pragma unroll
    for (int r = 0; r < 4; ++r) {
        int qout = qt * 64 + w * 16 + fq * 4 + r;
        float inv = 1.0f / lrow[r];
        unsigned short* yp = y + (size_t)(b * TT + qout) * NN + h * 64;
#pragma unroll
        for (int n = 0; n < 4; ++n)
            yp[n * 16 + fr] = f2bf(acco[n][r] * inv);
    }
}

// ---------------- logits: out[b,v] = dot(hf[b,T-1,:], wte[v,:]) ----------------
__global__ __launch_bounds__(256) void logits_kernel(const float* __restrict__ hf,
                                                     const float* __restrict__ wte,
                                                     float* __restrict__ out)
{
    __shared__ float hl[BB][NN];
    for (int i = threadIdx.x; i < BB * NN / 4; i += 256) {
        int b = i / (NN / 4), c = i % (NN / 4);
        ((float4*)&hl[b][0])[c] = ((const float4*)(hf + (size_t)(b * TT + TT - 1) * NN))[c];
    }
    __syncthreads();
    int w = threadIdx.x >> 6, lane = threadIdx.x & 63;
    const int NCH = (VV + 3) / 4;

    for (int cid = blockIdx.x * 4 + w; cid < NCH; cid += gridDim.x * 4) {
        int v0 = cid * 4;
        float4 wv[4][3];
#pragma unroll
        for (int r = 0; r < 4; ++r) {
            int v = min(v0 + r, VV - 1);
            const float4* wr4 = (const float4*)(wte + (size_t)v * NN);
#pragma unroll
            for (int i = 0; i < 3; ++i) wv[r][i] = wr4[i * 64 + lane];
        }
        float acc[4][BB];
#pragma unroll
        for (int r = 0; r < 4; ++r)
#pragma unroll
            for (int b = 0; b < BB; ++b) acc[r][b] = 0.f;
#pragma unroll
        for (int i = 0; i < 3; ++i) {
#pragma unroll
            for (int b = 0; b < BB; ++b) {
                float4 h4 = *(const float4*)&hl[b][i * 256 + lane * 4];
#pragma unroll
                for (int r = 0; r < 4; ++r)
                    acc[r][b] += wv[r][i].x * h4.x + wv[r][i].y * h4.y
                               + wv[r][i].z * h4.z + wv[r][i].w * h4.w;
            }
        }
#pragma unroll
        for (int off = 32; off; off >>= 1)
#pragma unroll
            for (int r = 0; r < 4; ++r)
#pragma unroll
                for (int b = 0; b < BB; ++b) acc[r][b] += __shfl_xor(acc[r][b], off);
        if (lane == 0) {
#pragma unroll
            for (int r = 0; r < 4; ++r) {
                int v = v0 + r;
                if (v < VV)
#pragma unroll
                    for (int b = 0; b < BB; ++b) out[(size_t)b * VV + v] = acc[r][b];
            }
        }
    }
}

extern "C" void kernel_launch(void* const* d_in, const int* in_sizes, int n_in,
                              void* d_out, int out_size, void* d_ws, size_t ws_size,
                              hipStream_t stream) {
    const int*   idx       = (const int*)d_in[0];
    const float* wte       = (const float*)d_in[1];
    const float* wpe       = (const float*)d_in[2];
    const float* step_emb  = (const float*)d_in[3];
    const float* ln1_w     = (const float*)d_in[4];
    const float* ln2_w     = (const float*)d_in[5];
    const float* lnf_w     = (const float*)d_in[6];
    const float* c_attn    = (const float*)d_in[7];
    const float* attn_proj = (const float*)d_in[8];
    const float* c_fc      = (const float*)d_in[9];
    const float* mlp_proj  = (const float*)d_in[10];
    float* out = (float*)d_out;

    float* ws = (float*)d_ws;
    const size_t RC = (size_t)MM * NN;
    float* x0  = ws;
    float* h   = ws + RC;
    float* hin = ws + 2 * RC;
    unsigned short* big = (unsigned short*)(ws + 3 * RC);
    unsigned short* lnb = (unsigned short*)(ws + 3 * RC + (size_t)MM * 3072 / 2);
    unsigned short* yb       = lnb + RC;
    unsigned short* cattn_bt = yb + RC;
    unsigned short* aproj_bt = cattn_bt + (size_t)2304 * 768;
    unsigned short* cfc_bt   = aproj_bt + (size_t)768 * 768;
    unsigned short* mproj_bt = cfc_bt + (size_t)768 * 3072;
    unsigned short* vT       = mproj_bt + (size_t)3072 * 768;   // [B*H*64][T]

    wconv_kernel<<<dim3(2304 / 32, 768 / 32), 256, 0, stream>>>(c_attn, cattn_bt, 768, 2304);
    wconv_kernel<<<dim3(768 / 32, 768 / 32), 256, 0, stream>>>(attn_proj, aproj_bt, 768, 768);
    wconv_kernel<<<dim3(3072 / 32, 768 / 32), 256, 0, stream>>>(c_fc, cfc_bt, 768, 3072);
    wconv_kernel<<<dim3(768 / 32, 3072 / 32), 256, 0, stream>>>(mlp_proj, mproj_bt, 3072, 768);

    embed_kernel<<<MM, 256, 0, stream>>>(idx, wte, wpe, x0, h);

    for (int l = 0; l < LL; ++l) {
        ln_kernel<true, unsigned short><<<MM, 256, 0, stream>>>(h, x0, step_emb + l * NN, ln1_w, hin, lnb);
        mgemm<128, 0, unsigned short><<<dim3(2304 / 128, MM / 128), 256, 0, stream>>>(lnb, cattn_bt, nullptr, big, 2304, 768);
        vtrans_kernel<<<dim3(TT / 64, HH, BB), 256, 0, stream>>>(big, vT);
        fattn_kernel<<<dim3(TT / 64, HH, BB), 256, 0, stream>>>(big, vT, yb);
        mgemm<64, 2, float><<<dim3(768 / 64, MM / 128), 256, 0, stream>>>(yb, aproj_bt, hin, hin, 768, 768);
        ln_kernel<false, unsigned short><<<MM, 256, 0, stream>>>(hin, nullptr, nullptr, ln2_w, nullptr, lnb);
        mgemm<128, 1, unsigned short><<<dim3(3072 / 128, MM / 128), 256, 0, stream>>>(lnb, cfc_bt, nullptr, big, 3072, 768);
        mgemm<64, 2, float><<<dim3(768 / 64, MM / 128), 256, 0, stream>>>(big, mproj_bt, hin, h, 768, 3072);
    }

    ln_kernel<false, float><<<MM, 256, 0, stream>>>(h, nullptr, nullptr, lnf_w, nullptr, x0);
    logits_kernel<<<1024, 256, 0, stream>>>(x0, wte, out);
}

// Round 6
// 2327.930 us; speedup vs baseline: 1.0794x; 1.0794x over previous
//
#include <hip/hip_runtime.h>
#include <hip/hip_bf16.h>
#include <math.h>

#define BB 8
#define TT 512
#define VV 50257
#define NN 768
#define HH 12
#define LL 12
#define MM (BB*TT)   // 4096 rows

typedef short bf16x8 __attribute__((ext_vector_type(8)));
typedef float f32x4 __attribute__((ext_vector_type(4)));
typedef unsigned short us8 __attribute__((ext_vector_type(8)));

__device__ __forceinline__ float bf2f(unsigned short u) {
    union { unsigned int i; float f; } x; x.i = ((unsigned int)u) << 16; return x.f;
}
__device__ __forceinline__ unsigned short f2bf(float f) {
    union { __hip_bfloat16 h; unsigned short u; } c; c.h = __float2bfloat16(f); return c.u;
}

// ---------------- embedding: x0 = wte[idx] + wpe ; h = x0 ----------------
__global__ void embed_kernel(const int* __restrict__ idx, const float* __restrict__ wte,
                             const float* __restrict__ wpe, float* __restrict__ x0,
                             float* __restrict__ h)
{
    int row = blockIdx.x;
    int t = row % TT;
    int tok = idx[row];
    const float* wt = wte + (size_t)tok * NN;
    const float* wp = wpe + (size_t)t * NN;
    float* px = x0 + (size_t)row * NN;
    float* ph = h  + (size_t)row * NN;
    for (int c = threadIdx.x; c < NN; c += blockDim.x) {
        float v = wt[c] + wp[c];
        px[c] = v; ph[c] = v;
    }
}

// ---------------- weight convert+transpose: W[K][Nc] fp32 -> Wt[Nc][K] bf16 ----------------
__global__ __launch_bounds__(256) void wconv_kernel(const float* __restrict__ W,
                                                    unsigned short* __restrict__ Wt,
                                                    int K, int Nc)
{
    __shared__ float tile[32][33];
    int n0 = blockIdx.x * 32, k0 = blockIdx.y * 32;
    int tid = threadIdx.x;
    int r = tid >> 3, c4 = (tid & 7) * 4;
    float4 v = *(const float4*)&W[(size_t)(k0 + r) * Nc + n0 + c4];
    tile[r][c4 + 0] = v.x; tile[r][c4 + 1] = v.y;
    tile[r][c4 + 2] = v.z; tile[r][c4 + 3] = v.w;
    __syncthreads();
    ushort4 o;
    o.x = f2bf(tile[c4 + 0][r]); o.y = f2bf(tile[c4 + 1][r]);
    o.z = f2bf(tile[c4 + 2][r]); o.w = f2bf(tile[c4 + 3][r]);
    *(ushort4*)&Wt[(size_t)(n0 + r) * K + k0 + c4] = o;
}

// ---------------- layernorm; ADD3 fuses hin = h + x0 + se ----------------
template<bool ADD3, typename OutT>
__global__ __launch_bounds__(256) void ln_kernel(
    const float* __restrict__ src, const float* __restrict__ x0,
    const float* __restrict__ se, const float* __restrict__ w,
    float* __restrict__ hin_out, OutT* __restrict__ out)
{
    int row = blockIdx.x;
    size_t base = (size_t)row * NN;
    int tid = threadIdx.x;
    float v[3];
    float s = 0.f, ss = 0.f;
#pragma unroll
    for (int i = 0; i < 3; ++i) {
        int c = tid + i * 256;
        float val = src[base + c];
        if (ADD3) { val += x0[base + c] + se[c]; hin_out[base + c] = val; }
        v[i] = val; s += val; ss += val * val;
    }
#pragma unroll
    for (int off = 32; off; off >>= 1) { s += __shfl_xor(s, off); ss += __shfl_xor(ss, off); }
    __shared__ float rs[4], rss[4], bc[2];
    int wid = tid >> 6, lane = tid & 63;
    if (lane == 0) { rs[wid] = s; rss[wid] = ss; }
    __syncthreads();
    if (tid == 0) {
        float S  = rs[0] + rs[1] + rs[2] + rs[3];
        float SS = rss[0] + rss[1] + rss[2] + rss[3];
        float mu = S / (float)NN;
        float var = SS / (float)NN - mu * mu;
        bc[0] = mu; bc[1] = rsqrtf(var + 1e-5f);
    }
    __syncthreads();
    float mu = bc[0], rsig = bc[1];
#pragma unroll
    for (int i = 0; i < 3; ++i) {
        int c = tid + i * 256;
        float o = (v[i] - mu) * rsig * w[c];
        if constexpr (sizeof(OutT) == 2) out[base + c] = (OutT)f2bf(o);
        else out[base + c] = o;
    }
}

// ---------------- bf16 MFMA GEMM, 3-buffer depth-2 pipeline, counted vmcnt ----------------
// C[M,N] = A[M,K] @ Bt[N,K]^T ; EPI: 0 none, 1 exact GELU, 2 residual add
// Per K-step: STAGE(t+2) -> vmcnt(2L) [t's loads done, t+1/t+2 in flight] ->
// barrier -> ds_read+MFMA on buf[t%3] -> barrier. Never vmcnt(0) in main loop.
template<int BN, int EPI, typename OutT>
__global__ __launch_bounds__(256) void mgemm(
    const unsigned short* __restrict__ A, const unsigned short* __restrict__ Bt,
    const float* __restrict__ res, OutT* __restrict__ C, int N, int K)
{
    constexpr int NF = BN / 32;              // col fragments per wave
    __shared__ unsigned short Asb[3][128 * 32];
    __shared__ unsigned short Bsb[3][BN * 32];
    int tid = threadIdx.x;
    int row0 = blockIdx.y * 128, col0 = blockIdx.x * BN;
    const unsigned short* Ap = A + (size_t)row0 * K;
    const unsigned short* Bp = Bt + (size_t)col0 * K;
    int lane = tid & 63, wid = tid >> 6;
    int wr = wid >> 1, wc = wid & 1;
    int fr = lane & 15, fq = lane >> 4;

    f32x4 acc[4][NF];
#pragma unroll
    for (int m = 0; m < 4; ++m)
#pragma unroll
        for (int n = 0; n < NF; ++n)
#pragma unroll
            for (int r = 0; r < 4; ++r) acc[m][n][r] = 0.f;

    int ldso = (tid & 192) * 8;   // wave-uniform LDS base (elems); HW adds lane*16B

    auto STAGE = [&](int buf, int k0) {
#pragma unroll
        for (int i = 0; i < 2; ++i) {
            int c = i * 256 + tid;              // row = c>>2, 16B piece = c&3
            __builtin_amdgcn_global_load_lds(
                (const __attribute__((address_space(1))) void*)(Ap + (size_t)(c >> 2) * K + k0 + (c & 3) * 8),
                (__attribute__((address_space(3))) void*)(Asb[buf] + i * 2048 + ldso), 16, 0, 0);
        }
        if constexpr (BN == 128) {
#pragma unroll
            for (int i = 0; i < 2; ++i) {
                int c = i * 256 + tid;
                __builtin_amdgcn_global_load_lds(
                    (const __attribute__((address_space(1))) void*)(Bp + (size_t)(c >> 2) * K + k0 + (c & 3) * 8),
                    (__attribute__((address_space(3))) void*)(Bsb[buf] + i * 2048 + ldso), 16, 0, 0);
            }
        } else {
            __builtin_amdgcn_global_load_lds(
                (const __attribute__((address_space(1))) void*)(Bp + (size_t)(tid >> 2) * K + k0 + (tid & 3) * 8),
                (__attribute__((address_space(3))) void*)(Bsb[buf] + ldso), 16, 0, 0);
        }
    };

    auto COMPUTE = [&](int buf) {
        const unsigned short* Ab = Asb[buf] + (wr * 64 + fr) * 32 + fq * 8;
        const unsigned short* Bb = Bsb[buf] + (wc * (BN / 2) + fr) * 32 + fq * 8;
        bf16x8 af[4], bfr[NF];
#pragma unroll
        for (int m = 0; m < 4; ++m) af[m] = *(const bf16x8*)(Ab + m * 512);
#pragma unroll
        for (int n = 0; n < NF; ++n) bfr[n] = *(const bf16x8*)(Bb + n * 512);
        __builtin_amdgcn_s_setprio(1);
#pragma unroll
        for (int m = 0; m < 4; ++m)
#pragma unroll
            for (int n = 0; n < NF; ++n)
                acc[m][n] = __builtin_amdgcn_mfma_f32_16x16x32_bf16(af[m], bfr[n], acc[m][n], 0, 0, 0);
        __builtin_amdgcn_s_setprio(0);
    };

    int NT = K / 32;                          // 24 or 96, always >= 3
    STAGE(0, 0);
    STAGE(1, 32);
    for (int t = 0; t < NT; ++t) {
        if (t + 2 < NT) {
            STAGE((t + 2) % 3, (t + 2) * 32);
            if constexpr (BN == 128) asm volatile("s_waitcnt vmcnt(8)" ::: "memory");
            else                     asm volatile("s_waitcnt vmcnt(6)" ::: "memory");
        } else if (t + 1 < NT) {
            if constexpr (BN == 128) asm volatile("s_waitcnt vmcnt(4)" ::: "memory");
            else                     asm volatile("s_waitcnt vmcnt(3)" ::: "memory");
        } else {
            asm volatile("s_waitcnt vmcnt(0)" ::: "memory");
        }
        __builtin_amdgcn_s_barrier();
        COMPUTE(t % 3);
        __builtin_amdgcn_s_barrier();
    }

#pragma unroll
    for (int m = 0; m < 4; ++m) {
#pragma unroll
        for (int n = 0; n < NF; ++n) {
            int col = col0 + wc * (BN / 2) + n * 16 + fr;
#pragma unroll
            for (int r = 0; r < 4; ++r) {
                int row = row0 + wr * 64 + m * 16 + fq * 4 + r;
                float v = acc[m][n][r];
                if (EPI == 1) v = 0.5f * v * (1.0f + erff(v * 0.70710678118654752f));
                if (EPI == 2) v += res[(size_t)row * N + col];
                if constexpr (sizeof(OutT) == 2) C[(size_t)row * N + col] = (OutT)f2bf(v);
                else C[(size_t)row * N + col] = v;
            }
        }
    }
}

// ---------------- flash MFMA attention (LDS-staged K/V, r4 structure) ----------------
__global__ __launch_bounds__(256) void fattn_kernel(const unsigned short* __restrict__ qkv,
                                                    unsigned short* __restrict__ y)
{
    int qt = blockIdx.x, h = blockIdx.y, b = blockIdx.z;
    int tid = threadIdx.x, lane = tid & 63, w = tid >> 6;
    int fr = lane & 15, fq = lane >> 4;

    __shared__ unsigned short Ks[64 * 72];
    __shared__ unsigned short Vts[64 * 72];
    __shared__ unsigned short Ps[64 * 72];

    int qrow = qt * 64 + w * 16 + fr;
    const unsigned short* qp = qkv + (size_t)(b * TT + qrow) * 2304 + h * 64 + fq * 8;
    bf16x8 qf0 = *(const bf16x8*)qp;
    bf16x8 qf1 = *(const bf16x8*)(qp + 32);

    f32x4 acco[4];
#pragma unroll
    for (int n = 0; n < 4; ++n)
#pragma unroll
        for (int r = 0; r < 4; ++r) acco[n][r] = 0.f;
    float mrow[4] = {-1e30f, -1e30f, -1e30f, -1e30f};
    float lrow[4] = {0.f, 0.f, 0.f, 0.f};

    for (int kt = 0; kt <= qt; ++kt) {
        __syncthreads();
        {
            int r = tid >> 2, c0 = (tid & 3) * 16;
            const us8* kp = (const us8*)&qkv[(size_t)(b * TT + kt * 64 + r) * 2304 + 768 + h * 64 + c0];
            us8 k0 = kp[0], k1 = kp[1];
            *(us8*)&Ks[r * 72 + c0] = k0;
            *(us8*)&Ks[r * 72 + c0 + 8] = k1;
            const us8* vp = (const us8*)&qkv[(size_t)(b * TT + kt * 64 + r) * 2304 + 1536 + h * 64 + c0];
            us8 v0 = vp[0], v1 = vp[1];
#pragma unroll
            for (int i = 0; i < 8; ++i) {
                Vts[(c0 + i) * 72 + r] = v0[i];
                Vts[(c0 + 8 + i) * 72 + r] = v1[i];
            }
        }
        __syncthreads();

        f32x4 accs[4];
#pragma unroll
        for (int n = 0; n < 4; ++n)
#pragma unroll
            for (int r = 0; r < 4; ++r) accs[n][r] = 0.f;
        {
            bf16x8 kf0[4], kf1[4];
#pragma unroll
            for (int n = 0; n < 4; ++n) {
                kf0[n] = *(const bf16x8*)&Ks[(n * 16 + fr) * 72 + fq * 8];
                kf1[n] = *(const bf16x8*)&Ks[(n * 16 + fr) * 72 + 32 + fq * 8];
            }
            __builtin_amdgcn_s_setprio(1);
#pragma unroll
            for (int n = 0; n < 4; ++n) {
                accs[n] = __builtin_amdgcn_mfma_f32_16x16x32_bf16(qf0, kf0[n], accs[n], 0, 0, 0);
                accs[n] = __builtin_amdgcn_mfma_f32_16x16x32_bf16(qf1, kf1[n], accs[n], 0, 0, 0);
            }
            __builtin_amdgcn_s_setprio(0);
        }

        bool diag = (kt == qt);
#pragma unroll
        for (int n = 0; n < 4; ++n) {
            int j = kt * 64 + n * 16 + fr;
#pragma unroll
            for (int r = 0; r < 4; ++r) {
                float s = accs[n][r] * 0.125f;
                if (diag) { int q = qt * 64 + w * 16 + fq * 4 + r; if (j > q) s = -1e30f; }
                accs[n][r] = s;
            }
        }

        float rmax[4], psum[4];
#pragma unroll
        for (int r = 0; r < 4; ++r) {
            float m = fmaxf(fmaxf(accs[0][r], accs[1][r]), fmaxf(accs[2][r], accs[3][r]));
#pragma unroll
            for (int off = 8; off; off >>= 1) m = fmaxf(m, __shfl_xor(m, off));
            rmax[r] = m;
        }
        float fac[4];
#pragma unroll
        for (int r = 0; r < 4; ++r) {
            float mn = fmaxf(mrow[r], rmax[r]);
            fac[r] = __expf(mrow[r] - mn);
            mrow[r] = mn;
            psum[r] = 0.f;
        }
#pragma unroll
        for (int n = 0; n < 4; ++n)
#pragma unroll
            for (int r = 0; r < 4; ++r) {
                float p = __expf(accs[n][r] - mrow[r]);
                accs[n][r] = p;
                psum[r] += p;
            }
#pragma unroll
        for (int r = 0; r < 4; ++r) {
#pragma unroll
            for (int off = 8; off; off >>= 1) psum[r] += __shfl_xor(psum[r], off);
            lrow[r] = lrow[r] * fac[r] + psum[r];
        }

#pragma unroll
        for (int n = 0; n < 4; ++n)
#pragma unroll
            for (int r = 0; r < 4; ++r)
                Ps[(w * 16 + fq * 4 + r) * 72 + n * 16 + fr] = f2bf(accs[n][r]);
#pragma unroll
        for (int n = 0; n < 4; ++n)
#pragma unroll
            for (int r = 0; r < 4; ++r) acco[n][r] *= fac[r];

        {
            bf16x8 pf0 = *(const bf16x8*)&Ps[(w * 16 + fr) * 72 + fq * 8];
            bf16x8 pf1 = *(const bf16x8*)&Ps[(w * 16 + fr) * 72 + 32 + fq * 8];
            bf16x8 vf0[4], vf1[4];
#pragma unroll
            for (int n = 0; n < 4; ++n) {
                vf0[n] = *(const bf16x8*)&Vts[(n * 16 + fr) * 72 + fq * 8];
                vf1[n] = *(const bf16x8*)&Vts[(n * 16 + fr) * 72 + 32 + fq * 8];
            }
            __builtin_amdgcn_s_setprio(1);
#pragma unroll
            for (int n = 0; n < 4; ++n) {
                acco[n] = __builtin_amdgcn_mfma_f32_16x16x32_bf16(pf0, vf0[n], acco[n], 0, 0, 0);
                acco[n] = __builtin_amdgcn_mfma_f32_16x16x32_bf16(pf1, vf1[n], acco[n], 0, 0, 0);
            }
            __builtin_amdgcn_s_setprio(0);
        }
    }

#pragma unroll
    for (int r = 0; r < 4; ++r) {
        int qout = qt * 64 + w * 16 + fq * 4 + r;
        float inv = 1.0f / lrow[r];
        unsigned short* yp = y + (size_t)(b * TT + qout) * NN + h * 64;
#pragma unroll
        for (int n = 0; n < 4; ++n)
            yp[n * 16 + fr] = f2bf(acco[n][r] * inv);
    }
}

// ---------------- logits: out[b,v] = dot(hf[b,T-1,:], wte[v,:]) ----------------
__global__ __launch_bounds__(256) void logits_kernel(const float* __restrict__ hf,
                                                     const float* __restrict__ wte,
                                                     float* __restrict__ out)
{
    __shared__ float hl[BB][NN];
    for (int i = threadIdx.x; i < BB * NN / 4; i += 256) {
        int b = i / (NN / 4), c = i % (NN / 4);
        ((float4*)&hl[b][0])[c] = ((const float4*)(hf + (size_t)(b * TT + TT - 1) * NN))[c];
    }
    __syncthreads();
    int w = threadIdx.x >> 6, lane = threadIdx.x & 63;
    const int NCH = (VV + 3) / 4;

    for (int cid = blockIdx.x * 4 + w; cid < NCH; cid += gridDim.x * 4) {
        int v0 = cid * 4;
        float4 wv[4][3];
#pragma unroll
        for (int r = 0; r < 4; ++r) {
            int v = min(v0 + r, VV - 1);
            const float4* wr4 = (const float4*)(wte + (size_t)v * NN);
#pragma unroll
            for (int i = 0; i < 3; ++i) wv[r][i] = wr4[i * 64 + lane];
        }
        float acc[4][BB];
#pragma unroll
        for (int r = 0; r < 4; ++r)
#pragma unroll
            for (int b = 0; b < BB; ++b) acc[r][b] = 0.f;
#pragma unroll
        for (int i = 0; i < 3; ++i) {
#pragma unroll
            for (int b = 0; b < BB; ++b) {
                float4 h4 = *(const float4*)&hl[b][i * 256 + lane * 4];
#pragma unroll
                for (int r = 0; r < 4; ++r)
                    acc[r][b] += wv[r][i].x * h4.x + wv[r][i].y * h4.y
                               + wv[r][i].z * h4.z + wv[r][i].w * h4.w;
            }
        }
#pragma unroll
        for (int off = 32; off; off >>= 1)
#pragma unroll
            for (int r = 0; r < 4; ++r)
#pragma unroll
                for (int b = 0; b < BB; ++b) acc[r][b] += __shfl_xor(acc[r][b], off);
        if (lane == 0) {
#pragma unroll
            for (int r = 0; r < 4; ++r) {
                int v = v0 + r;
                if (v < VV)
#pragma unroll
                    for (int b = 0; b < BB; ++b) out[(size_t)b * VV + v] = acc[r][b];
            }
        }
    }
}

extern "C" void kernel_launch(void* const* d_in, const int* in_sizes, int n_in,
                              void* d_out, int out_size, void* d_ws, size_t ws_size,
                              hipStream_t stream) {
    const int*   idx       = (const int*)d_in[0];
    const float* wte       = (const float*)d_in[1];
    const float* wpe       = (const float*)d_in[2];
    const float* step_emb  = (const float*)d_in[3];
    const float* ln1_w     = (const float*)d_in[4];
    const float* ln2_w     = (const float*)d_in[5];
    const float* lnf_w     = (const float*)d_in[6];
    const float* c_attn    = (const float*)d_in[7];
    const float* attn_proj = (const float*)d_in[8];
    const float* c_fc      = (const float*)d_in[9];
    const float* mlp_proj  = (const float*)d_in[10];
    float* out = (float*)d_out;

    float* ws = (float*)d_ws;
    const size_t RC = (size_t)MM * NN;
    float* x0  = ws;
    float* h   = ws + RC;
    float* hin = ws + 2 * RC;
    unsigned short* big = (unsigned short*)(ws + 3 * RC);
    unsigned short* lnb = (unsigned short*)(ws + 3 * RC + (size_t)MM * 3072 / 2);
    unsigned short* yb       = lnb + RC;
    unsigned short* cattn_bt = yb + RC;
    unsigned short* aproj_bt = cattn_bt + (size_t)2304 * 768;
    unsigned short* cfc_bt   = aproj_bt + (size_t)768 * 768;
    unsigned short* mproj_bt = cfc_bt + (size_t)768 * 3072;

    wconv_kernel<<<dim3(2304 / 32, 768 / 32), 256, 0, stream>>>(c_attn, cattn_bt, 768, 2304);
    wconv_kernel<<<dim3(768 / 32, 768 / 32), 256, 0, stream>>>(attn_proj, aproj_bt, 768, 768);
    wconv_kernel<<<dim3(3072 / 32, 768 / 32), 256, 0, stream>>>(c_fc, cfc_bt, 768, 3072);
    wconv_kernel<<<dim3(768 / 32, 3072 / 32), 256, 0, stream>>>(mlp_proj, mproj_bt, 3072, 768);

    embed_kernel<<<MM, 256, 0, stream>>>(idx, wte, wpe, x0, h);

    for (int l = 0; l < LL; ++l) {
        ln_kernel<true, unsigned short><<<MM, 256, 0, stream>>>(h, x0, step_emb + l * NN, ln1_w, hin, lnb);
        mgemm<128, 0, unsigned short><<<dim3(2304 / 128, MM / 128), 256, 0, stream>>>(lnb, cattn_bt, nullptr, big, 2304, 768);
        fattn_kernel<<<dim3(TT / 64, HH, BB), 256, 0, stream>>>(big, yb);
        mgemm<64, 2, float><<<dim3(768 / 64, MM / 128), 256, 0, stream>>>(yb, aproj_bt, hin, hin, 768, 768);
        ln_kernel<false, unsigned short><<<MM, 256, 0, stream>>>(hin, nullptr, nullptr, ln2_w, nullptr, lnb);
        mgemm<128, 1, unsigned short><<<dim3(3072 / 128, MM / 128), 256, 0, stream>>>(lnb, cfc_bt, nullptr, big, 3072, 768);
        mgemm<64, 2, float><<<dim3(768 / 64, MM / 128), 256, 0, stream>>>(big, mproj_bt, hin, h, 768, 3072);
    }

    ln_kernel<false, float><<<MM, 256, 0, stream>>>(h, nullptr, nullptr, lnf_w, nullptr, x0);
    logits_kernel<<<1024, 256, 0, stream>>>(x0, wte, out);
}

// Round 7
// 2293.379 us; speedup vs baseline: 1.0957x; 1.0151x over previous
//
#include <hip/hip_runtime.h>
#include <hip/hip_bf16.h>
#include <math.h>

#define BB 8
#define TT 512
#define VV 50257
#define NN 768
#define HH 12
#define LL 12
#define MM (BB*TT)   // 4096 rows

typedef short bf16x8 __attribute__((ext_vector_type(8)));
typedef float f32x4 __attribute__((ext_vector_type(4)));
typedef unsigned short us8 __attribute__((ext_vector_type(8)));

__device__ __forceinline__ float bf2f(unsigned short u) {
    union { unsigned int i; float f; } x; x.i = ((unsigned int)u) << 16; return x.f;
}
__device__ __forceinline__ unsigned short f2bf(float f) {
    union { __hip_bfloat16 h; unsigned short u; } c; c.h = __float2bfloat16(f); return c.u;
}

// ---------------- embedding: x0 = wte[idx] + wpe ; h = x0 ----------------
__global__ void embed_kernel(const int* __restrict__ idx, const float* __restrict__ wte,
                             const float* __restrict__ wpe, float* __restrict__ x0,
                             float* __restrict__ h)
{
    int row = blockIdx.x;
    int t = row % TT;
    int tok = idx[row];
    const float* wt = wte + (size_t)tok * NN;
    const float* wp = wpe + (size_t)t * NN;
    float* px = x0 + (size_t)row * NN;
    float* ph = h  + (size_t)row * NN;
    for (int c = threadIdx.x; c < NN; c += blockDim.x) {
        float v = wt[c] + wp[c];
        px[c] = v; ph[c] = v;
    }
}

// ---------------- weight convert+transpose: W[K][Nc] fp32 -> Wt[Nc][K] bf16 ----------------
__global__ __launch_bounds__(256) void wconv_kernel(const float* __restrict__ W,
                                                    unsigned short* __restrict__ Wt,
                                                    int K, int Nc)
{
    __shared__ float tile[32][33];
    int n0 = blockIdx.x * 32, k0 = blockIdx.y * 32;
    int tid = threadIdx.x;
    int r = tid >> 3, c4 = (tid & 7) * 4;
    float4 v = *(const float4*)&W[(size_t)(k0 + r) * Nc + n0 + c4];
    tile[r][c4 + 0] = v.x; tile[r][c4 + 1] = v.y;
    tile[r][c4 + 2] = v.z; tile[r][c4 + 3] = v.w;
    __syncthreads();
    ushort4 o;
    o.x = f2bf(tile[c4 + 0][r]); o.y = f2bf(tile[c4 + 1][r]);
    o.z = f2bf(tile[c4 + 2][r]); o.w = f2bf(tile[c4 + 3][r]);
    *(ushort4*)&Wt[(size_t)(n0 + r) * K + k0 + c4] = o;
}

// ---------------- layernorm; ADD3 fuses hin = h + x0 + se ----------------
template<bool ADD3, typename OutT>
__global__ __launch_bounds__(256) void ln_kernel(
    const float* __restrict__ src, const float* __restrict__ x0,
    const float* __restrict__ se, const float* __restrict__ w,
    float* __restrict__ hin_out, OutT* __restrict__ out)
{
    int row = blockIdx.x;
    size_t base = (size_t)row * NN;
    int tid = threadIdx.x;
    float v[3];
    float s = 0.f, ss = 0.f;
#pragma unroll
    for (int i = 0; i < 3; ++i) {
        int c = tid + i * 256;
        float val = src[base + c];
        if (ADD3) { val += x0[base + c] + se[c]; hin_out[base + c] = val; }
        v[i] = val; s += val; ss += val * val;
    }
#pragma unroll
    for (int off = 32; off; off >>= 1) { s += __shfl_xor(s, off); ss += __shfl_xor(ss, off); }
    __shared__ float rs[4], rss[4], bc[2];
    int wid = tid >> 6, lane = tid & 63;
    if (lane == 0) { rs[wid] = s; rss[wid] = ss; }
    __syncthreads();
    if (tid == 0) {
        float S  = rs[0] + rs[1] + rs[2] + rs[3];
        float SS = rss[0] + rss[1] + rss[2] + rss[3];
        float mu = S / (float)NN;
        float var = SS / (float)NN - mu * mu;
        bc[0] = mu; bc[1] = rsqrtf(var + 1e-5f);
    }
    __syncthreads();
    float mu = bc[0], rsig = bc[1];
#pragma unroll
    for (int i = 0; i < 3; ++i) {
        int c = tid + i * 256;
        float o = (v[i] - mu) * rsig * w[c];
        if constexpr (sizeof(OutT) == 2) out[base + c] = (OutT)f2bf(o);
        else out[base + c] = o;
    }
}

// ---------------- bf16 MFMA GEMM, 3-buffer depth-2 pipeline, counted vmcnt ----------------
template<int BN, int EPI, typename OutT>
__global__ __launch_bounds__(256) void mgemm(
    const unsigned short* __restrict__ A, const unsigned short* __restrict__ Bt,
    const float* __restrict__ res, OutT* __restrict__ C, int N, int K)
{
    constexpr int NF = BN / 32;              // col fragments per wave
    __shared__ unsigned short Asb[3][128 * 32];
    __shared__ unsigned short Bsb[3][BN * 32];
    int tid = threadIdx.x;
    int row0 = blockIdx.y * 128, col0 = blockIdx.x * BN;
    const unsigned short* Ap = A + (size_t)row0 * K;
    const unsigned short* Bp = Bt + (size_t)col0 * K;
    int lane = tid & 63, wid = tid >> 6;
    int wr = wid >> 1, wc = wid & 1;
    int fr = lane & 15, fq = lane >> 4;

    f32x4 acc[4][NF];
#pragma unroll
    for (int m = 0; m < 4; ++m)
#pragma unroll
        for (int n = 0; n < NF; ++n)
#pragma unroll
            for (int r = 0; r < 4; ++r) acc[m][n][r] = 0.f;

    int ldso = (tid & 192) * 8;

    auto STAGE = [&](int buf, int k0) {
#pragma unroll
        for (int i = 0; i < 2; ++i) {
            int c = i * 256 + tid;
            __builtin_amdgcn_global_load_lds(
                (const __attribute__((address_space(1))) void*)(Ap + (size_t)(c >> 2) * K + k0 + (c & 3) * 8),
                (__attribute__((address_space(3))) void*)(Asb[buf] + i * 2048 + ldso), 16, 0, 0);
        }
        if constexpr (BN == 128) {
#pragma unroll
            for (int i = 0; i < 2; ++i) {
                int c = i * 256 + tid;
                __builtin_amdgcn_global_load_lds(
                    (const __attribute__((address_space(1))) void*)(Bp + (size_t)(c >> 2) * K + k0 + (c & 3) * 8),
                    (__attribute__((address_space(3))) void*)(Bsb[buf] + i * 2048 + ldso), 16, 0, 0);
            }
        } else {
            __builtin_amdgcn_global_load_lds(
                (const __attribute__((address_space(1))) void*)(Bp + (size_t)(tid >> 2) * K + k0 + (tid & 3) * 8),
                (__attribute__((address_space(3))) void*)(Bsb[buf] + ldso), 16, 0, 0);
        }
    };

    auto COMPUTE = [&](int buf) {
        const unsigned short* Ab = Asb[buf] + (wr * 64 + fr) * 32 + fq * 8;
        const unsigned short* Bb = Bsb[buf] + (wc * (BN / 2) + fr) * 32 + fq * 8;
        bf16x8 af[4], bfr[NF];
#pragma unroll
        for (int m = 0; m < 4; ++m) af[m] = *(const bf16x8*)(Ab + m * 512);
#pragma unroll
        for (int n = 0; n < NF; ++n) bfr[n] = *(const bf16x8*)(Bb + n * 512);
        __builtin_amdgcn_s_setprio(1);
#pragma unroll
        for (int m = 0; m < 4; ++m)
#pragma unroll
            for (int n = 0; n < NF; ++n)
                acc[m][n] = __builtin_amdgcn_mfma_f32_16x16x32_bf16(af[m], bfr[n], acc[m][n], 0, 0, 0);
        __builtin_amdgcn_s_setprio(0);
    };

    int NT = K / 32;
    STAGE(0, 0);
    STAGE(1, 32);
    for (int t = 0; t < NT; ++t) {
        if (t + 2 < NT) {
            STAGE((t + 2) % 3, (t + 2) * 32);
            if constexpr (BN == 128) asm volatile("s_waitcnt vmcnt(8)" ::: "memory");
            else                     asm volatile("s_waitcnt vmcnt(6)" ::: "memory");
        } else if (t + 1 < NT) {
            if constexpr (BN == 128) asm volatile("s_waitcnt vmcnt(4)" ::: "memory");
            else                     asm volatile("s_waitcnt vmcnt(3)" ::: "memory");
        } else {
            asm volatile("s_waitcnt vmcnt(0)" ::: "memory");
        }
        __builtin_amdgcn_s_barrier();
        COMPUTE(t % 3);
        __builtin_amdgcn_s_barrier();
    }

#pragma unroll
    for (int m = 0; m < 4; ++m) {
#pragma unroll
        for (int n = 0; n < NF; ++n) {
            int col = col0 + wc * (BN / 2) + n * 16 + fr;
#pragma unroll
            for (int r = 0; r < 4; ++r) {
                int row = row0 + wr * 64 + m * 16 + fq * 4 + r;
                float v = acc[m][n][r];
                if (EPI == 1) v = 0.5f * v * (1.0f + erff(v * 0.70710678118654752f));
                if (EPI == 2) v += res[(size_t)row * N + col];
                if constexpr (sizeof(OutT) == 2) C[(size_t)row * N + col] = (OutT)f2bf(v);
                else C[(size_t)row * N + col] = v;
            }
        }
    }
}

// ---------------- flash MFMA attention ----------------
// Double-buffered K/V (1 barrier/tile), async-stage split (global loads issued
// before compute, LDS writes after), swizzled V^T stores: col' = t ^ (((d>>4)&3)<<4)
// spreads the 4 d-column-groups across all 32 banks (was 8-way conflicted).
__global__ __launch_bounds__(256) void fattn_kernel(const unsigned short* __restrict__ qkv,
                                                    unsigned short* __restrict__ y)
{
    int qt = blockIdx.x, h = blockIdx.y, b = blockIdx.z;
    int tid = threadIdx.x, lane = tid & 63, w = tid >> 6;
    int fr = lane & 15, fq = lane >> 4;

    __shared__ unsigned short Ks[2][64 * 72];
    __shared__ unsigned short Vts[2][64 * 72];
    __shared__ unsigned short Ps[64 * 72];

    int qrow = qt * 64 + w * 16 + fr;
    const unsigned short* qp = qkv + (size_t)(b * TT + qrow) * 2304 + h * 64 + fq * 8;
    bf16x8 qf0 = *(const bf16x8*)qp;
    bf16x8 qf1 = *(const bf16x8*)(qp + 32);

    int sr = tid >> 2;              // key index t within tile, 0..63
    int sc = (tid & 3) * 16;        // d base

    f32x4 acco[4];
#pragma unroll
    for (int n = 0; n < 4; ++n)
#pragma unroll
        for (int r = 0; r < 4; ++r) acco[n][r] = 0.f;
    float mrow[4] = {-1e30f, -1e30f, -1e30f, -1e30f};
    float lrow[4] = {0.f, 0.f, 0.f, 0.f};

    us8 kr0, kr1, vr0, vr1;
    {   // tile 0: load + write + barrier
        const us8* kp = (const us8*)&qkv[(size_t)(b * TT + sr) * 2304 + 768 + h * 64 + sc];
        kr0 = kp[0]; kr1 = kp[1];
        const us8* vp = (const us8*)&qkv[(size_t)(b * TT + sr) * 2304 + 1536 + h * 64 + sc];
        vr0 = vp[0]; vr1 = vp[1];
        *(us8*)&Ks[0][sr * 72 + sc] = kr0;
        *(us8*)&Ks[0][sr * 72 + sc + 8] = kr1;
#pragma unroll
        for (int i = 0; i < 8; ++i) {
            int d0 = sc + i, d1 = sc + 8 + i;
            Vts[0][d0 * 72 + (sr ^ (((d0 >> 4) & 3) << 4))] = vr0[i];
            Vts[0][d1 * 72 + (sr ^ (((d1 >> 4) & 3) << 4))] = vr1[i];
        }
    }
    __syncthreads();

    for (int kt = 0; kt <= qt; ++kt) {
        int cur = kt & 1;
        bool pre = (kt < qt);
        if (pre) {  // issue next tile's global loads early; write to LDS after compute
            const us8* kp = (const us8*)&qkv[(size_t)(b * TT + (kt + 1) * 64 + sr) * 2304 + 768 + h * 64 + sc];
            kr0 = kp[0]; kr1 = kp[1];
            const us8* vp = (const us8*)&qkv[(size_t)(b * TT + (kt + 1) * 64 + sr) * 2304 + 1536 + h * 64 + sc];
            vr0 = vp[0]; vr1 = vp[1];
        }

        // S = Q K^T
        f32x4 accs[4];
#pragma unroll
        for (int n = 0; n < 4; ++n)
#pragma unroll
            for (int r = 0; r < 4; ++r) accs[n][r] = 0.f;
        {
            bf16x8 kf0[4], kf1[4];
#pragma unroll
            for (int n = 0; n < 4; ++n) {
                kf0[n] = *(const bf16x8*)&Ks[cur][(n * 16 + fr) * 72 + fq * 8];
                kf1[n] = *(const bf16x8*)&Ks[cur][(n * 16 + fr) * 72 + 32 + fq * 8];
            }
            __builtin_amdgcn_s_setprio(1);
#pragma unroll
            for (int n = 0; n < 4; ++n) {
                accs[n] = __builtin_amdgcn_mfma_f32_16x16x32_bf16(qf0, kf0[n], accs[n], 0, 0, 0);
                accs[n] = __builtin_amdgcn_mfma_f32_16x16x32_bf16(qf1, kf1[n], accs[n], 0, 0, 0);
            }
            __builtin_amdgcn_s_setprio(0);
        }

        bool diag = (kt == qt);
#pragma unroll
        for (int n = 0; n < 4; ++n) {
            int j = kt * 64 + n * 16 + fr;
#pragma unroll
            for (int r = 0; r < 4; ++r) {
                float s = accs[n][r] * 0.125f;
                if (diag) { int q = qt * 64 + w * 16 + fq * 4 + r; if (j > q) s = -1e30f; }
                accs[n][r] = s;
            }
        }

        // online softmax (reduce across 16 fr lanes per q-row)
        float rmax[4], psum[4];
#pragma unroll
        for (int r = 0; r < 4; ++r) {
            float m = fmaxf(fmaxf(accs[0][r], accs[1][r]), fmaxf(accs[2][r], accs[3][r]));
#pragma unroll
            for (int off = 8; off; off >>= 1) m = fmaxf(m, __shfl_xor(m, off));
            rmax[r] = m;
        }
        float fac[4];
#pragma unroll
        for (int r = 0; r < 4; ++r) {
            float mn = fmaxf(mrow[r], rmax[r]);
            fac[r] = __expf(mrow[r] - mn);
            mrow[r] = mn;
            psum[r] = 0.f;
        }
#pragma unroll
        for (int n = 0; n < 4; ++n)
#pragma unroll
            for (int r = 0; r < 4; ++r) {
                float p = __expf(accs[n][r] - mrow[r]);
                accs[n][r] = p;
                psum[r] += p;
            }
#pragma unroll
        for (int r = 0; r < 4; ++r) {
#pragma unroll
            for (int off = 8; off; off >>= 1) psum[r] += __shfl_xor(psum[r], off);
            lrow[r] = lrow[r] * fac[r] + psum[r];
        }

        // P -> LDS (wave-private), rescale O
#pragma unroll
        for (int n = 0; n < 4; ++n)
#pragma unroll
            for (int r = 0; r < 4; ++r)
                Ps[(w * 16 + fq * 4 + r) * 72 + n * 16 + fr] = f2bf(accs[n][r]);
#pragma unroll
        for (int n = 0; n < 4; ++n)
#pragma unroll
            for (int r = 0; r < 4; ++r) acco[n][r] *= fac[r];

        // PV: O += P @ V  (V^T rows read with matching swizzle; 8-runs preserved)
        {
            bf16x8 pf0 = *(const bf16x8*)&Ps[(w * 16 + fr) * 72 + fq * 8];
            bf16x8 pf1 = *(const bf16x8*)&Ps[(w * 16 + fr) * 72 + 32 + fq * 8];
            bf16x8 vf0[4], vf1[4];
#pragma unroll
            for (int n = 0; n < 4; ++n) {
                int cA = (fq * 8) ^ (n << 4);
                int cB = (32 + fq * 8) ^ (n << 4);
                vf0[n] = *(const bf16x8*)&Vts[cur][(n * 16 + fr) * 72 + cA];
                vf1[n] = *(const bf16x8*)&Vts[cur][(n * 16 + fr) * 72 + cB];
            }
            __builtin_amdgcn_s_setprio(1);
#pragma unroll
            for (int n = 0; n < 4; ++n) {
                acco[n] = __builtin_amdgcn_mfma_f32_16x16x32_bf16(pf0, vf0[n], acco[n], 0, 0, 0);
                acco[n] = __builtin_amdgcn_mfma_f32_16x16x32_bf16(pf1, vf1[n], acco[n], 0, 0, 0);
            }
            __builtin_amdgcn_s_setprio(0);
        }

        if (pre) {  // write next tile to the other buffer
            *(us8*)&Ks[cur ^ 1][sr * 72 + sc] = kr0;
            *(us8*)&Ks[cur ^ 1][sr * 72 + sc + 8] = kr1;
#pragma unroll
            for (int i = 0; i < 8; ++i) {
                int d0 = sc + i, d1 = sc + 8 + i;
                Vts[cur ^ 1][d0 * 72 + (sr ^ (((d0 >> 4) & 3) << 4))] = vr0[i];
                Vts[cur ^ 1][d1 * 72 + (sr ^ (((d1 >> 4) & 3) << 4))] = vr1[i];
            }
        }
        __syncthreads();
    }

#pragma unroll
    for (int r = 0; r < 4; ++r) {
        int qout = qt * 64 + w * 16 + fq * 4 + r;
        float inv = 1.0f / lrow[r];
        unsigned short* yp = y + (size_t)(b * TT + qout) * NN + h * 64;
#pragma unroll
        for (int n = 0; n < 4; ++n)
            yp[n * 16 + fr] = f2bf(acco[n][r] * inv);
    }
}

// ---------------- logits: out[b,v] = dot(hf[b,T-1,:], wte[v,:]) ----------------
__global__ __launch_bounds__(256) void logits_kernel(const float* __restrict__ hf,
                                                     const float* __restrict__ wte,
                                                     float* __restrict__ out)
{
    __shared__ float hl[BB][NN];
    for (int i = threadIdx.x; i < BB * NN / 4; i += 256) {
        int b = i / (NN / 4), c = i % (NN / 4);
        ((float4*)&hl[b][0])[c] = ((const float4*)(hf + (size_t)(b * TT + TT - 1) * NN))[c];
    }
    __syncthreads();
    int w = threadIdx.x >> 6, lane = threadIdx.x & 63;
    const int NCH = (VV + 3) / 4;

    for (int cid = blockIdx.x * 4 + w; cid < NCH; cid += gridDim.x * 4) {
        int v0 = cid * 4;
        float4 wv[4][3];
#pragma unroll
        for (int r = 0; r < 4; ++r) {
            int v = min(v0 + r, VV - 1);
            const float4* wr4 = (const float4*)(wte + (size_t)v * NN);
#pragma unroll
            for (int i = 0; i < 3; ++i) wv[r][i] = wr4[i * 64 + lane];
        }
        float acc[4][BB];
#pragma unroll
        for (int r = 0; r < 4; ++r)
#pragma unroll
            for (int b = 0; b < BB; ++b) acc[r][b] = 0.f;
#pragma unroll
        for (int i = 0; i < 3; ++i) {
#pragma unroll
            for (int b = 0; b < BB; ++b) {
                float4 h4 = *(const float4*)&hl[b][i * 256 + lane * 4];
#pragma unroll
                for (int r = 0; r < 4; ++r)
                    acc[r][b] += wv[r][i].x * h4.x + wv[r][i].y * h4.y
                               + wv[r][i].z * h4.z + wv[r][i].w * h4.w;
            }
        }
#pragma unroll
        for (int off = 32; off; off >>= 1)
#pragma unroll
            for (int r = 0; r < 4; ++r)
#pragma unroll
                for (int b = 0; b < BB; ++b) acc[r][b] += __shfl_xor(acc[r][b], off);
        if (lane == 0) {
#pragma unroll
            for (int r = 0; r < 4; ++r) {
                int v = v0 + r;
                if (v < VV)
#pragma unroll
                    for (int b = 0; b < BB; ++b) out[(size_t)b * VV + v] = acc[r][b];
            }
        }
    }
}

extern "C" void kernel_launch(void* const* d_in, const int* in_sizes, int n_in,
                              void* d_out, int out_size, void* d_ws, size_t ws_size,
                              hipStream_t stream) {
    const int*   idx       = (const int*)d_in[0];
    const float* wte       = (const float*)d_in[1];
    const float* wpe       = (const float*)d_in[2];
    const float* step_emb  = (const float*)d_in[3];
    const float* ln1_w     = (const float*)d_in[4];
    const float* ln2_w     = (const float*)d_in[5];
    const float* lnf_w     = (const float*)d_in[6];
    const float* c_attn    = (const float*)d_in[7];
    const float* attn_proj = (const float*)d_in[8];
    const float* c_fc      = (const float*)d_in[9];
    const float* mlp_proj  = (const float*)d_in[10];
    float* out = (float*)d_out;

    float* ws = (float*)d_ws;
    const size_t RC = (size_t)MM * NN;
    float* x0  = ws;
    float* h   = ws + RC;
    float* hin = ws + 2 * RC;
    unsigned short* big = (unsigned short*)(ws + 3 * RC);
    unsigned short* lnb = (unsigned short*)(ws + 3 * RC + (size_t)MM * 3072 / 2);
    unsigned short* yb       = lnb + RC;
    unsigned short* cattn_bt = yb + RC;
    unsigned short* aproj_bt = cattn_bt + (size_t)2304 * 768;
    unsigned short* cfc_bt   = aproj_bt + (size_t)768 * 768;
    unsigned short* mproj_bt = cfc_bt + (size_t)768 * 3072;

    wconv_kernel<<<dim3(2304 / 32, 768 / 32), 256, 0, stream>>>(c_attn, cattn_bt, 768, 2304);
    wconv_kernel<<<dim3(768 / 32, 768 / 32), 256, 0, stream>>>(attn_proj, aproj_bt, 768, 768);
    wconv_kernel<<<dim3(3072 / 32, 768 / 32), 256, 0, stream>>>(c_fc, cfc_bt, 768, 3072);
    wconv_kernel<<<dim3(768 / 32, 3072 / 32), 256, 0, stream>>>(mlp_proj, mproj_bt, 3072, 768);

    embed_kernel<<<MM, 256, 0, stream>>>(idx, wte, wpe, x0, h);

    for (int l = 0; l < LL; ++l) {
        ln_kernel<true, unsigned short><<<MM, 256, 0, stream>>>(h, x0, step_emb + l * NN, ln1_w, hin, lnb);
        mgemm<128, 0, unsigned short><<<dim3(2304 / 128, MM / 128), 256, 0, stream>>>(lnb, cattn_bt, nullptr, big, 2304, 768);
        fattn_kernel<<<dim3(TT / 64, HH, BB), 256, 0, stream>>>(big, yb);
        mgemm<64, 2, float><<<dim3(768 / 64, MM / 128), 256, 0, stream>>>(yb, aproj_bt, hin, hin, 768, 768);
        ln_kernel<false, unsigned short><<<MM, 256, 0, stream>>>(hin, nullptr, nullptr, ln2_w, nullptr, lnb);
        mgemm<128, 1, unsigned short><<<dim3(3072 / 128, MM / 128), 256, 0, stream>>>(lnb, cfc_bt, nullptr, big, 3072, 768);
        mgemm<64, 2, float><<<dim3(768 / 64, MM / 128), 256, 0, stream>>>(big, mproj_bt, hin, h, 768, 3072);
    }

    ln_kernel<false, float><<<MM, 256, 0, stream>>>(h, nullptr, nullptr, lnf_w, nullptr, x0);
    logits_kernel<<<1024, 256, 0, stream>>>(x0, wte, out);
}